// Round 1
// baseline (1248.906 us; speedup 1.0000x reference)
//
#include <hip/hip_runtime.h>
#include <math.h>

// Problem constants (fixed by setup_inputs): T=2, B=32, Nt=196(14x14), D=768,
// heads=12, hd=64, H_s=W_s=96, N_s=9217 (incl. CLS at index 0).
#define TT 2
#define BB 32
#define DD 768
#define HEADS 12
#define HD 64
#define HT 14
#define WT 14
#define HS 96
#define WS 96
#define NS (HS*WS)        // 9216
#define NSK (NS+1)        // 9217
#define SMW (WS-WT+1)     // 83
#define SMH (HS-HT+1)     // 83

// ---------------------------------------------------------------------------
// Kernel 1: per-(t,b) masked proto pooling. grid = (3 d-chunks, T, B), 256 thr.
// protos[t][b][d] = sum_{masked cells} patches[t,b,cell,d] / (count + 1e-6)
// ---------------------------------------------------------------------------
__global__ __launch_bounds__(256) void proto_kernel(
    const float* __restrict__ patches, const float* __restrict__ annos,
    float* __restrict__ protos) {
  const int dc = blockIdx.x, t = blockIdx.y, b = blockIdx.z;
  const int d = dc * 256 + threadIdx.x;

  const float* an = annos + (t * BB + b) * 4;
  const float ax = an[0], ay = an[1], aw = an[2], ah = an[3];
  const int x1 = (int)floorf(ax * (float)WT);
  const int y1 = (int)floorf(ay * (float)HT);
  const int x2 = (int)floorf((ax + aw) * (float)WT);
  const int y2 = (int)floorf((ay + ah) * (float)HT);
  const int cx2 = min(x2, WT), cy2 = min(y2, HT);
  const int cw = max(cx2 - x1, 0), ch = max(cy2 - y1, 0);
  const float count = (float)(cw * ch);

  float s = 0.f;
  const float* base = patches + ((size_t)(t * BB + b)) * (HT*WT) * DD + d;
  for (int r = y1; r < cy2; ++r)
    for (int c = x1; c < cx2; ++c)
      s += base[(r * WT + c) * DD];

  protos[(size_t)(t * BB + b) * DD + d] = s / (count + 1e-6f);
}

// ---------------------------------------------------------------------------
// Kernel 2: attention + head-mean. grid = (36, B), 256 thr; one thread per n.
// track[b][n] = (1/heads) * 0.125 * sum_{h,d} proto[b,h*64+d]*sk[b,h,n+1,d]
// ---------------------------------------------------------------------------
__global__ __launch_bounds__(256) void attn_kernel(
    const float* __restrict__ sk, const float* __restrict__ protos,
    float* __restrict__ track) {
  __shared__ float sp[DD];
  const int b = blockIdx.y;
  const int n = blockIdx.x * 256 + threadIdx.x;  // 0..9215

  for (int i = threadIdx.x; i < DD; i += 256)
    sp[i] = 0.5f * (protos[(size_t)b * DD + i] +
                    protos[(size_t)(BB + b) * DD + i]);
  __syncthreads();

  float acc = 0.f;
  const float* skb = sk + (size_t)b * HEADS * NSK * HD;
  #pragma unroll
  for (int h = 0; h < HEADS; ++h) {
    const float4* v = (const float4*)(skb + ((size_t)h * NSK + (n + 1)) * HD);
    const float* p = sp + h * HD;
    #pragma unroll
    for (int q = 0; q < HD / 4; ++q) {
      float4 x = v[q];
      acc += p[4*q+0]*x.x + p[4*q+1]*x.y + p[4*q+2]*x.z + p[4*q+3]*x.w;
    }
  }
  track[(size_t)b * NS + n] = acc * 0.125f / 12.0f;
}

// ---------------------------------------------------------------------------
// Kernel 3: blur + softmax + integral image + box-argmax. One block per b.
// Single LDS image buffer P[97*97] (stride 97 -> <=2 lanes/bank).
// ---------------------------------------------------------------------------
__device__ __forceinline__ int reflect96(int p) {
  return p < 0 ? -p : (p > 95 ? 190 - p : p);
}

__global__ __launch_bounds__(256) void post_kernel(
    const float* __restrict__ track, float* __restrict__ out) {
  __shared__ float P[97 * 97];
  __shared__ float red[256];
  __shared__ int redi[256];
  const int b = blockIdx.x, tid = threadIdx.x;

  // Gaussian weights, sigma=1.1 (matches ref: exp(-r^2/(2*1.21)) normalized)
  const float e2 = expf(-4.0f / (2.0f * 1.1f * 1.1f));
  const float e1 = expf(-1.0f / (2.0f * 1.1f * 1.1f));
  const float wsum = 2.f * e2 + 2.f * e1 + 1.f;
  const float w0 = e2 / wsum, w1 = e1 / wsum, w2 = 1.f / wsum;

  const float* tr = track + (size_t)b * NS;

  // vertical blur (reflect), read from global (L1-resident) -> P[r*97+c]
  for (int i = tid; i < NS; i += 256) {
    const int r = i / WS, c = i % WS;
    float acc = w2 * tr[r * WS + c];
    acc += w1 * (tr[reflect96(r - 1) * WS + c] + tr[reflect96(r + 1) * WS + c]);
    acc += w0 * (tr[reflect96(r - 2) * WS + c] + tr[reflect96(r + 2) * WS + c]);
    P[r * 97 + c] = acc;
  }
  __syncthreads();

  // horizontal blur -> registers (36 pixels/thread)
  float vals[36];
  #pragma unroll
  for (int k = 0; k < 36; ++k) {
    const int i = tid + k * 256;
    const int r = i / WS, c = i % WS;
    float acc = w2 * P[r * 97 + c];
    acc += w1 * (P[r * 97 + reflect96(c - 1)] + P[r * 97 + reflect96(c + 1)]);
    acc += w0 * (P[r * 97 + reflect96(c - 2)] + P[r * 97 + reflect96(c + 2)]);
    vals[k] = acc;
  }
  __syncthreads();

  // softmax over all 9216
  float lm = -1e30f;
  #pragma unroll
  for (int k = 0; k < 36; ++k) lm = fmaxf(lm, vals[k]);
  red[tid] = lm; __syncthreads();
  for (int s = 128; s > 0; s >>= 1) {
    if (tid < s) red[tid] = fmaxf(red[tid], red[tid + s]);
    __syncthreads();
  }
  const float m = red[0]; __syncthreads();

  float ls = 0.f;
  #pragma unroll
  for (int k = 0; k < 36; ++k) { vals[k] = expf(vals[k] - m); ls += vals[k]; }
  red[tid] = ls; __syncthreads();
  for (int s = 128; s > 0; s >>= 1) {
    if (tid < s) red[tid] += red[tid + s];
    __syncthreads();
  }
  const float inv = 1.0f / red[0]; __syncthreads();

  // write prob to out; store shifted into P interior for the integral image
  float* prob_out = out + 5 * BB + (size_t)b * NS;
  #pragma unroll
  for (int k = 0; k < 36; ++k) {
    const int i = tid + k * 256;
    const int r = i / WS, c = i % WS;
    const float p = vals[k] * inv;
    prob_out[i] = p;
    P[(r + 1) * 97 + (c + 1)] = p;
  }
  // zero pad row 0 / col 0
  for (int i = tid; i < 97; i += 256) { P[i] = 0.f; P[i * 97] = 0.f; }
  __syncthreads();

  // in-place column prefix (cols 1..96)
  if (tid < 96) {
    const int c = tid + 1;
    float run = P[97 + c];
    for (int r = 2; r < 97; ++r) { run += P[r * 97 + c]; P[r * 97 + c] = run; }
  }
  __syncthreads();
  // in-place row prefix (rows 1..96)
  if (tid < 96) {
    const int r = tid + 1;
    float run = 0.f;
    for (int c = 1; c < 97; ++c) { run += P[r * 97 + c]; P[r * 97 + c] = run; }
  }
  __syncthreads();

  // argmax over 83x83 box sums (first-occurrence tie-break like jnp.argmax)
  float bv = -1e30f; int bi = 0x7fffffff;
  for (int i = tid; i < SMH * SMW; i += 256) {
    const int y = i / SMW, x = i % SMW;
    const float v = P[(y + HT) * 97 + (x + WT)] - P[y * 97 + (x + WT)]
                  - P[(y + HT) * 97 + x] + P[y * 97 + x];
    if (v > bv || (v == bv && i < bi)) { bv = v; bi = i; }
  }
  red[tid] = bv; redi[tid] = bi; __syncthreads();
  for (int s = 128; s > 0; s >>= 1) {
    if (tid < s) {
      const float ov = red[tid + s]; const int oi = redi[tid + s];
      if (ov > red[tid] || (ov == red[tid] && oi < redi[tid])) {
        red[tid] = ov; redi[tid] = oi;
      }
    }
    __syncthreads();
  }

  if (tid == 0) {
    const int idx = redi[0];
    out[0 * BB + b] = (float)(idx % SMW);   // best_x
    out[1 * BB + b] = (float)(idx / SMW);   // best_y
    out[2 * BB + b] = (float)WT;            // win_w
    out[3 * BB + b] = (float)HT;            // win_h
    out[4 * BB + b] = red[0];               // confidence
  }
}

// ---------------------------------------------------------------------------
extern "C" void kernel_launch(void* const* d_in, const int* in_sizes, int n_in,
                              void* d_out, int out_size, void* d_ws, size_t ws_size,
                              hipStream_t stream) {
  (void)in_sizes; (void)n_in; (void)out_size; (void)ws_size;
  const float* patches = (const float*)d_in[0];
  const float* annos   = (const float*)d_in[1];
  const float* sk      = (const float*)d_in[2];
  float* ws = (float*)d_ws;
  float* protos = ws;                         // TT*BB*DD = 49152 floats
  float* track  = ws + (size_t)TT * BB * DD;  // BB*NS  = 294912 floats
  float* out = (float*)d_out;

  proto_kernel<<<dim3(DD / 256, TT, BB), 256, 0, stream>>>(patches, annos, protos);
  attn_kernel<<<dim3(NS / 256, BB), 256, 0, stream>>>(sk, protos, track);
  post_kernel<<<BB, 256, 0, stream>>>(track, out);
}

// Round 2
// 1196.415 us; speedup vs baseline: 1.0439x; 1.0439x over previous
//
#include <hip/hip_runtime.h>
#include <math.h>

// Problem constants (fixed by setup_inputs): T=2, B=32, Nt=196(14x14), D=768,
// heads=12, hd=64, H_s=W_s=96, N_s=9217 (incl. CLS at index 0).
// search_key = 32*12*9217*64 f32 = 906 MB -> attn kernel is the HBM stream.
#define TT 2
#define BB 32
#define DD 768
#define HEADS 12
#define HD 64
#define HT 14
#define WT 14
#define HS 96
#define WS 96
#define NS (HS*WS)        // 9216
#define NSK (NS+1)        // 9217
#define SMW (WS-WT+1)     // 83
#define SMH (HS-HT+1)     // 83

// ---------------------------------------------------------------------------
// Kernel 1: per-(t,b) masked proto pooling. grid = (3 d-chunks, T, B), 256 thr.
// protos[t][b][d] = sum_{masked cells} patches[t,b,cell,d] / (count + 1e-6)
// Coalesced: lane d reads consecutive floats for each masked cell.
// ---------------------------------------------------------------------------
__global__ __launch_bounds__(256) void proto_kernel(
    const float* __restrict__ patches, const float* __restrict__ annos,
    float* __restrict__ protos) {
  const int dc = blockIdx.x, t = blockIdx.y, b = blockIdx.z;
  const int d = dc * 256 + threadIdx.x;

  const float* an = annos + (t * BB + b) * 4;
  const float ax = an[0], ay = an[1], aw = an[2], ah = an[3];
  const int x1 = (int)floorf(ax * (float)WT);
  const int y1 = (int)floorf(ay * (float)HT);
  const int x2 = (int)floorf((ax + aw) * (float)WT);
  const int y2 = (int)floorf((ay + ah) * (float)HT);
  const int cx2 = min(x2, WT), cy2 = min(y2, HT);
  const int cw = max(cx2 - x1, 0), ch = max(cy2 - y1, 0);
  const float count = (float)(cw * ch);

  float s = 0.f;
  const float* base = patches + ((size_t)(t * BB + b)) * (HT*WT) * DD + d;
  for (int r = y1; r < cy2; ++r)
    for (int c = x1; c < cx2; ++c)
      s += base[(r * WT + c) * DD];

  protos[(size_t)(t * BB + b) * DD + d] = s / (count + 1e-6f);
}

// ---------------------------------------------------------------------------
// Kernel 2: attention + head-mean, coalesced. grid = (144, B), 256 thr.
// A 16-lane group owns one search row n: lane (tid&15) reads d-slice
// [4*(tid&15), +4) for each head -> each wave instr reads 1 KB contiguous.
// Partial dots reduced with shfl_xor(1,2,4,8) within the 16-lane group.
// track[b][n] = (1/12) * 64^-0.5 * sum_{h,d} proto[b,h*64+d]*sk[b,h,n+1,d]
// ---------------------------------------------------------------------------
__global__ __launch_bounds__(256) void attn_kernel(
    const float* __restrict__ sk, const float* __restrict__ protos,
    float* __restrict__ track) {
  const int b = blockIdx.y;
  const int tid = threadIdx.x;
  const int lane16 = tid & 15;       // d-slice within head
  const int grp = tid >> 4;          // 0..15 row subgroup within block
  const int n0 = blockIdx.x * 64;    // block covers rows n0..n0+63

  // Preload proto slice (avg over T) into registers: 12 heads x 4 floats.
  float4 pr[HEADS];
  const float4* p0 = (const float4*)(protos + (size_t)b * DD);
  const float4* p1 = (const float4*)(protos + (size_t)(BB + b) * DD);
  #pragma unroll
  for (int h = 0; h < HEADS; ++h) {
    float4 a = p0[h * 16 + lane16];
    float4 c = p1[h * 16 + lane16];
    pr[h] = make_float4(0.5f * (a.x + c.x), 0.5f * (a.y + c.y),
                        0.5f * (a.z + c.z), 0.5f * (a.w + c.w));
  }

  const float* skb = sk + (size_t)b * HEADS * NSK * HD;
  float acc[4] = {0.f, 0.f, 0.f, 0.f};
  #pragma unroll
  for (int j = 0; j < 4; ++j) {
    const int row = n0 + 16 * j + grp;   // 0..9215
    const float4* base = (const float4*)(skb + (size_t)(row + 1) * HD) + lane16;
    #pragma unroll
    for (int h = 0; h < HEADS; ++h) {
      float4 v = base[h * (NSK * HD / 4)];
      acc[j] += v.x * pr[h].x + v.y * pr[h].y + v.z * pr[h].z + v.w * pr[h].w;
    }
  }

  #pragma unroll
  for (int j = 0; j < 4; ++j) {
    #pragma unroll
    for (int s = 1; s < 16; s <<= 1)
      acc[j] += __shfl_xor(acc[j], s, 64);
    if (lane16 == 0)
      track[(size_t)b * NS + n0 + 16 * j + grp] = acc[j] * (1.0f / 96.0f);
  }
}

// ---------------------------------------------------------------------------
// Kernel 3: blur + softmax + integral image + box-argmax. One block per b.
// Single LDS image buffer P[97*97] (stride 97 -> <=2 lanes/bank).
// ---------------------------------------------------------------------------
__device__ __forceinline__ int reflect96(int p) {
  return p < 0 ? -p : (p > 95 ? 190 - p : p);
}

__global__ __launch_bounds__(256) void post_kernel(
    const float* __restrict__ track, float* __restrict__ out) {
  __shared__ float P[97 * 97];
  __shared__ float red[256];
  __shared__ int redi[256];
  const int b = blockIdx.x, tid = threadIdx.x;

  // Gaussian weights, sigma=1.1 (matches ref: exp(-r^2/(2*1.21)) normalized)
  const float e2 = expf(-4.0f / (2.0f * 1.1f * 1.1f));
  const float e1 = expf(-1.0f / (2.0f * 1.1f * 1.1f));
  const float wsum = 2.f * e2 + 2.f * e1 + 1.f;
  const float w0 = e2 / wsum, w1 = e1 / wsum, w2 = 1.f / wsum;

  const float* tr = track + (size_t)b * NS;

  // vertical blur (reflect), read from global (L1/L2-resident)
  for (int i = tid; i < NS; i += 256) {
    const int r = i / WS, c = i % WS;
    float acc = w2 * tr[r * WS + c];
    acc += w1 * (tr[reflect96(r - 1) * WS + c] + tr[reflect96(r + 1) * WS + c]);
    acc += w0 * (tr[reflect96(r - 2) * WS + c] + tr[reflect96(r + 2) * WS + c]);
    P[r * 97 + c] = acc;
  }
  __syncthreads();

  // horizontal blur -> registers (36 pixels/thread)
  float vals[36];
  #pragma unroll
  for (int k = 0; k < 36; ++k) {
    const int i = tid + k * 256;
    const int r = i / WS, c = i % WS;
    float acc = w2 * P[r * 97 + c];
    acc += w1 * (P[r * 97 + reflect96(c - 1)] + P[r * 97 + reflect96(c + 1)]);
    acc += w0 * (P[r * 97 + reflect96(c - 2)] + P[r * 97 + reflect96(c + 2)]);
    vals[k] = acc;
  }
  __syncthreads();

  // softmax over all 9216
  float lm = -1e30f;
  #pragma unroll
  for (int k = 0; k < 36; ++k) lm = fmaxf(lm, vals[k]);
  red[tid] = lm; __syncthreads();
  for (int s = 128; s > 0; s >>= 1) {
    if (tid < s) red[tid] = fmaxf(red[tid], red[tid + s]);
    __syncthreads();
  }
  const float m = red[0]; __syncthreads();

  float ls = 0.f;
  #pragma unroll
  for (int k = 0; k < 36; ++k) { vals[k] = expf(vals[k] - m); ls += vals[k]; }
  red[tid] = ls; __syncthreads();
  for (int s = 128; s > 0; s >>= 1) {
    if (tid < s) red[tid] += red[tid + s];
    __syncthreads();
  }
  const float inv = 1.0f / red[0]; __syncthreads();

  // write prob to out; store shifted into P interior for the integral image
  float* prob_out = out + 5 * BB + (size_t)b * NS;
  #pragma unroll
  for (int k = 0; k < 36; ++k) {
    const int i = tid + k * 256;
    const int r = i / WS, c = i % WS;
    const float p = vals[k] * inv;
    prob_out[i] = p;
    P[(r + 1) * 97 + (c + 1)] = p;
  }
  for (int i = tid; i < 97; i += 256) { P[i] = 0.f; P[i * 97] = 0.f; }
  __syncthreads();

  // in-place column prefix (cols 1..96) — loads independent, adds pipelined
  if (tid < 96) {
    const int c = tid + 1;
    float run = P[97 + c];
    for (int r = 2; r < 97; ++r) { run += P[r * 97 + c]; P[r * 97 + c] = run; }
  }
  __syncthreads();
  // in-place row prefix (rows 1..96)
  if (tid < 96) {
    const int r = tid + 1;
    float run = 0.f;
    for (int c = 1; c < 97; ++c) { run += P[r * 97 + c]; P[r * 97 + c] = run; }
  }
  __syncthreads();

  // argmax over 83x83 box sums (first-occurrence tie-break like jnp.argmax)
  float bv = -1e30f; int bi = 0x7fffffff;
  for (int i = tid; i < SMH * SMW; i += 256) {
    const int y = i / SMW, x = i % SMW;
    const float v = P[(y + HT) * 97 + (x + WT)] - P[y * 97 + (x + WT)]
                  - P[(y + HT) * 97 + x] + P[y * 97 + x];
    if (v > bv || (v == bv && i < bi)) { bv = v; bi = i; }
  }
  red[tid] = bv; redi[tid] = bi; __syncthreads();
  for (int s = 128; s > 0; s >>= 1) {
    if (tid < s) {
      const float ov = red[tid + s]; const int oi = redi[tid + s];
      if (ov > red[tid] || (ov == red[tid] && oi < redi[tid])) {
        red[tid] = ov; redi[tid] = oi;
      }
    }
    __syncthreads();
  }

  if (tid == 0) {
    const int idx = redi[0];
    out[0 * BB + b] = (float)(idx % SMW);   // best_x
    out[1 * BB + b] = (float)(idx / SMW);   // best_y
    out[2 * BB + b] = (float)WT;            // win_w
    out[3 * BB + b] = (float)HT;            // win_h
    out[4 * BB + b] = red[0];               // confidence
  }
}

// ---------------------------------------------------------------------------
extern "C" void kernel_launch(void* const* d_in, const int* in_sizes, int n_in,
                              void* d_out, int out_size, void* d_ws, size_t ws_size,
                              hipStream_t stream) {
  (void)in_sizes; (void)n_in; (void)out_size; (void)ws_size;
  const float* patches = (const float*)d_in[0];
  const float* annos   = (const float*)d_in[1];
  const float* sk      = (const float*)d_in[2];
  float* ws = (float*)d_ws;
  float* protos = ws;                         // TT*BB*DD = 49152 floats
  float* track  = ws + (size_t)TT * BB * DD;  // BB*NS  = 294912 floats
  float* out = (float*)d_out;

  proto_kernel<<<dim3(DD / 256, TT, BB), 256, 0, stream>>>(patches, annos, protos);
  attn_kernel<<<dim3(NS / 64, BB), 256, 0, stream>>>(sk, protos, track);
  post_kernel<<<BB, 256, 0, stream>>>(track, out);
}